// Round 10
// baseline (65.380 us; speedup 1.0000x reference)
//
#include <hip/hip_runtime.h>

#define N_NODES 100000
#define N_EDGES 6400000
#define RANGES 8
#define RANGE_S 12500   // nodes per range; RANGES * RANGE_S == N_NODES
#define NB 64           // chunks; chunk = 100000 edges
#define BLK 1024
#define FIX_SCALE 1048576.0f        // 2^20
#define FIX_INV   (1.0f / 1048576.0f)

// transform_v2 geometry
#define TBLOCKS 256
#define TTHREADS 1024
#define EPB (N_EDGES / TBLOCKS)     // 25000 edges per block
#define GPB (EPB / 8)               // 3125 groups of 8
#define QS 25000                    // nodes per quarter (x staged in 100KB LDS)
#define NQ 4

// ============ fallback path A: direct device atomics ============
__global__ void zero_out_kernel(float* __restrict__ out, int n) {
    int i = blockIdx.x * blockDim.x + threadIdx.x;
    if (i < n) out[i] = 0.0f;
}

__global__ void __launch_bounds__(256) scatter_direct_kernel(
        const float* __restrict__ x, const int* __restrict__ ei,
        const float* __restrict__ w, float* __restrict__ out) {
    int t = blockIdx.x * blockDim.x + threadIdx.x;
    int e0 = t * 4;
    if (e0 >= N_EDGES) return;
    int4   s4 = *reinterpret_cast<const int4*>(ei + e0);
    int4   d4 = *reinterpret_cast<const int4*>(ei + N_EDGES + e0);
    float4 w4 = *reinterpret_cast<const float4*>(w + e0);
    atomicAdd(&out[s4.x], w4.x * x[d4.x]);
    atomicAdd(&out[s4.y], w4.y * x[d4.y]);
    atomicAdd(&out[s4.z], w4.z * x[d4.z]);
    atomicAdd(&out[s4.w], w4.w * x[d4.w]);
}

// ============ main path ============
__device__ __forceinline__ unsigned bf16_rne(float f) {
    unsigned b = __float_as_uint(f);
    b += 0x7FFFu + ((b >> 16) & 1u);
    return b >> 16;
}

// Phase 1 v2: LDS-staged gather. Block owns 25000 edges, holds dst/w in regs,
// loops over 4 x-quarters staged exactly (f32) in 100KB LDS. Each edge's dst
// is in exactly one quarter -> OR its bf16 msg into the packed word there.
__global__ void __launch_bounds__(TTHREADS) transform_kernel(
        const float* __restrict__ x, const int* __restrict__ ei,
        const float* __restrict__ w, unsigned short* __restrict__ msg) {
    __shared__ float xq[QS];          // 100 KB
    const int b   = blockIdx.x;
    const int tid = threadIdx.x;
    const int base = b * EPB;
    const int* dstp = ei + N_EDGES;

    // Load this thread's up-to-4 groups of 8 edges (dst + w) into registers.
    int4  da[4], db[4];
    float4 wa[4], wb[4];
    uint4 o[4];
    bool  valid[4];
    #pragma unroll
    for (int k = 0; k < 4; ++k) {
        int idx = k * TTHREADS + tid;
        valid[k] = (idx < GPB);
        int e0 = base + idx * 8;
        if (valid[k]) {
            da[k] = *reinterpret_cast<const int4*>(dstp + e0);
            db[k] = *reinterpret_cast<const int4*>(dstp + e0 + 4);
            wa[k] = *reinterpret_cast<const float4*>(w + e0);
            wb[k] = *reinterpret_cast<const float4*>(w + e0 + 4);
        } else {
            da[k] = db[k] = make_int4(0,0,0,0);
            wa[k] = wb[k] = make_float4(0.f,0.f,0.f,0.f);
        }
        o[k] = make_uint4(0u,0u,0u,0u);
    }

    #pragma unroll
    for (int q = 0; q < NQ; ++q) {
        __syncthreads();              // previous pass's LDS reads complete
        // stage quarter q: 25000 floats, coalesced float4
        const float4* src4 = reinterpret_cast<const float4*>(x + q * QS);
        for (int j = tid; j < QS / 4; j += TTHREADS) {
            *reinterpret_cast<float4*>(&xq[j * 4]) = src4[j];
        }
        __syncthreads();
        const int qlo = q * QS;

        #pragma unroll
        for (int k = 0; k < 4; ++k) {
            // 8 edges: da[k].{x,y,z,w}, db[k].{x,y,z,w}
            unsigned a0 = (unsigned)(da[k].x - qlo), a1 = (unsigned)(da[k].y - qlo),
                     a2 = (unsigned)(da[k].z - qlo), a3 = (unsigned)(da[k].w - qlo),
                     a4 = (unsigned)(db[k].x - qlo), a5 = (unsigned)(db[k].y - qlo),
                     a6 = (unsigned)(db[k].z - qlo), a7 = (unsigned)(db[k].w - qlo);
            float v0 = xq[a0 < QS ? a0 : 0u], v1 = xq[a1 < QS ? a1 : 0u],
                  v2 = xq[a2 < QS ? a2 : 0u], v3 = xq[a3 < QS ? a3 : 0u],
                  v4 = xq[a4 < QS ? a4 : 0u], v5 = xq[a5 < QS ? a5 : 0u],
                  v6 = xq[a6 < QS ? a6 : 0u], v7 = xq[a7 < QS ? a7 : 0u];
            o[k].x |= (a0 < QS ? bf16_rne(wa[k].x * v0)        : 0u)
                    | (a1 < QS ? bf16_rne(wa[k].y * v1) << 16  : 0u);
            o[k].y |= (a2 < QS ? bf16_rne(wa[k].z * v2)        : 0u)
                    | (a3 < QS ? bf16_rne(wa[k].w * v3) << 16  : 0u);
            o[k].z |= (a4 < QS ? bf16_rne(wb[k].x * v4)        : 0u)
                    | (a5 < QS ? bf16_rne(wb[k].y * v5) << 16  : 0u);
            o[k].w |= (a6 < QS ? bf16_rne(wb[k].z * v6)        : 0u)
                    | (a7 < QS ? bf16_rne(wb[k].w * v7) << 16  : 0u);
        }
    }

    #pragma unroll
    for (int k = 0; k < 4; ++k) {
        int idx = k * TTHREADS + tid;
        if (valid[k]) {
            *reinterpret_cast<uint4*>(msg + base + idx * 8) = o[k];
        }
    }
}

// Phase 2: int32 fixed-point bins (R9-proven), 2 blocks/CU, XCD-sibling swizzle.
__global__ void __launch_bounds__(BLK) bin_kernel(
        const int* __restrict__ ei, const unsigned short* __restrict__ msg,
        int* __restrict__ partial) {
    __shared__ int bins[RANGE_S];   // 50 KB
    const int b    = blockIdx.x;    // 0..511
    const int xcd  = b & 7;
    const int slot = b >> 3;        // 0..63
    const int r    = slot & 7;      // range
    const int c    = (slot >> 3) * 8 + xcd;  // chunk 0..63 (siblings share XCD)

    for (int i = threadIdx.x; i < RANGE_S; i += BLK) bins[i] = 0;
    __syncthreads();

    const int chunk = N_EDGES / NB;   // 100000, % 8 == 0
    const int base  = c * chunk;
    const int end   = base + chunk;
    const int lo    = r * RANGE_S;

    for (int e = base + (int)threadIdx.x * 8; e < end; e += BLK * 8) {
        int4 sa = *reinterpret_cast<const int4*>(ei + e);
        int4 sb = *reinterpret_cast<const int4*>(ei + e + 4);
        uint4 mm = *reinterpret_cast<const uint4*>(msg + e);

        unsigned a[8] = {(unsigned)(sa.x-lo),(unsigned)(sa.y-lo),(unsigned)(sa.z-lo),(unsigned)(sa.w-lo),
                         (unsigned)(sb.x-lo),(unsigned)(sb.y-lo),(unsigned)(sb.z-lo),(unsigned)(sb.w-lo)};
        float f[8] = {
            __uint_as_float((mm.x & 0xFFFFu) << 16), __uint_as_float(mm.x & 0xFFFF0000u),
            __uint_as_float((mm.y & 0xFFFFu) << 16), __uint_as_float(mm.y & 0xFFFF0000u),
            __uint_as_float((mm.z & 0xFFFFu) << 16), __uint_as_float(mm.z & 0xFFFF0000u),
            __uint_as_float((mm.w & 0xFFFFu) << 16), __uint_as_float(mm.w & 0xFFFF0000u)
        };
        int mi[8];
        #pragma unroll
        for (int k = 0; k < 8; ++k) mi[k] = (int)__builtin_rintf(f[k] * FIX_SCALE);
        #pragma unroll
        for (int k = 0; k < 8; ++k) {
            if (a[k] < RANGE_S) atomicAdd(&bins[a[k]], mi[k]);   // integer LDS atomic
        }
    }
    __syncthreads();
    int* outp = partial + (size_t)(r * NB + c) * RANGE_S;
    for (int i = threadIdx.x; i < RANGE_S; i += BLK) outp[i] = bins[i];
}

// Reduce: exact integer sum of 64 chunk-partials, single float convert.
__global__ void reduce_range_kernel(const int* __restrict__ partial, float* __restrict__ out) {
    int i = blockIdx.x * blockDim.x + threadIdx.x;
    int n0 = i * 4;
    if (n0 >= N_NODES) return;
    int r = n0 / RANGE_S;
    int s = n0 - r * RANGE_S;          // RANGE_S % 4 == 0 -> no straddle
    const int* base = partial + (size_t)(r * NB) * RANGE_S + s;
    int4 acc = make_int4(0, 0, 0, 0);
    for (int j = 0; j < NB; ++j) {
        int4 v = *reinterpret_cast<const int4*>(base + (size_t)j * RANGE_S);
        acc.x += v.x; acc.y += v.y; acc.z += v.z; acc.w += v.w;
    }
    float4 o = make_float4((float)acc.x * FIX_INV, (float)acc.y * FIX_INV,
                           (float)acc.z * FIX_INV, (float)acc.w * FIX_INV);
    *reinterpret_cast<float4*>(out + n0) = o;
}

extern "C" void kernel_launch(void* const* d_in, const int* in_sizes, int n_in,
                              void* d_out, int out_size, void* d_ws, size_t ws_size,
                              hipStream_t stream) {
    const float* x   = (const float*)d_in[0];
    const int*   ei  = (const int*)d_in[1];
    const float* w   = (const float*)d_in[2];
    float*       out = (float*)d_out;

    const size_t msg_bytes     = (size_t)N_EDGES * 2;                 // 12.8 MB
    const size_t partial_bytes = (size_t)RANGES * NB * RANGE_S * 4;   // 25.6 MB

    if (ws_size >= msg_bytes + partial_bytes) {
        unsigned short* msg = (unsigned short*)d_ws;
        int* partial = (int*)((char*)d_ws + msg_bytes);
        transform_kernel<<<TBLOCKS, TTHREADS, 0, stream>>>(x, ei, w, msg);
        bin_kernel<<<RANGES * NB, BLK, 0, stream>>>(ei, msg, partial);
        reduce_range_kernel<<<(N_NODES / 4 + 255) / 256, 256, 0, stream>>>(partial, out);
    } else {
        zero_out_kernel<<<(N_NODES + 255) / 256, 256, 0, stream>>>(out, N_NODES);
        scatter_direct_kernel<<<(N_EDGES / 4 + 255) / 256, 256, 0, stream>>>(x, ei, w, out);
    }
}

// Round 11
// 48.169 us; speedup vs baseline: 1.3573x; 1.3573x over previous
//
#include <hip/hip_runtime.h>

#define N_NODES 100000
#define N_EDGES 6400000
#define RANGES 8
#define RANGE_S 12500   // nodes per range; RANGES * RANGE_S == N_NODES
#define NB 64           // chunks; chunk = 100000 edges
#define BLK 1024
#define FIX_SCALE 1048576.0f        // 2^20
#define FIX_INV   (1.0f / 1048576.0f)

// transform v3 geometry
#define TBLOCKS 256
#define TTHREADS 1024
#define EPB (N_EDGES / TBLOCKS)     // 25000 edges per block
#define GPB (EPB / 8)               // 3125 groups of 8
#define HALF_S 50000                // nodes per half (bf16 -> 100 KB LDS)
#define NP 2

// ============ fallback path A: direct device atomics ============
__global__ void zero_out_kernel(float* __restrict__ out, int n) {
    int i = blockIdx.x * blockDim.x + threadIdx.x;
    if (i < n) out[i] = 0.0f;
}

__global__ void __launch_bounds__(256) scatter_direct_kernel(
        const float* __restrict__ x, const int* __restrict__ ei,
        const float* __restrict__ w, float* __restrict__ out) {
    int t = blockIdx.x * blockDim.x + threadIdx.x;
    int e0 = t * 4;
    if (e0 >= N_EDGES) return;
    int4   s4 = *reinterpret_cast<const int4*>(ei + e0);
    int4   d4 = *reinterpret_cast<const int4*>(ei + N_EDGES + e0);
    float4 w4 = *reinterpret_cast<const float4*>(w + e0);
    atomicAdd(&out[s4.x], w4.x * x[d4.x]);
    atomicAdd(&out[s4.y], w4.y * x[d4.y]);
    atomicAdd(&out[s4.z], w4.z * x[d4.z]);
    atomicAdd(&out[s4.w], w4.w * x[d4.w]);
}

// ============ main path ============
__device__ __forceinline__ unsigned bf16_rne(float f) {
    unsigned b = __float_as_uint(f);
    b += 0x7FFFu + ((b >> 16) & 1u);
    return b >> 16;
}
__device__ __forceinline__ float bf16_to_f(unsigned short h) {
    return __uint_as_float(((unsigned)h) << 16);
}

// Phase 1 v3: LDS-staged gather, spill-free.
// 2 passes over bf16 x-halves (100 KB LDS each). dst/w re-read per pass
// (pass 1 from L3). Only the packed msg accumulator o[4] (16 VGPR) persists.
__global__ void __launch_bounds__(TTHREADS, 4) transform_kernel(
        const float* __restrict__ x, const int* __restrict__ ei,
        const float* __restrict__ w, unsigned short* __restrict__ msg) {
    __shared__ unsigned short xh[HALF_S];   // 100 KB
    const int tid  = threadIdx.x;
    const int base = blockIdx.x * EPB;
    const int* dstp = ei + N_EDGES;

    uint4 o[4];
    #pragma unroll
    for (int k = 0; k < 4; ++k) o[k] = make_uint4(0u, 0u, 0u, 0u);

    #pragma unroll
    for (int p = 0; p < NP; ++p) {
        if (p) __syncthreads();             // prior pass's LDS reads done
        // stage half p: 50000 floats -> bf16, coalesced
        const float4* xs = reinterpret_cast<const float4*>(x + p * HALF_S);
        for (int j = tid; j < HALF_S / 8; j += TTHREADS) {
            float4 f0 = xs[j * 2], f1 = xs[j * 2 + 1];
            uint4 pk;
            pk.x = bf16_rne(f0.x) | (bf16_rne(f0.y) << 16);
            pk.y = bf16_rne(f0.z) | (bf16_rne(f0.w) << 16);
            pk.z = bf16_rne(f1.x) | (bf16_rne(f1.y) << 16);
            pk.w = bf16_rne(f1.z) | (bf16_rne(f1.w) << 16);
            *reinterpret_cast<uint4*>(&xh[j * 8]) = pk;
        }
        __syncthreads();
        const int lo = p * HALF_S;

        #pragma unroll
        for (int k = 0; k < 4; ++k) {
            int idx = k * TTHREADS + tid;
            if (idx < GPB) {
                int e0 = base + idx * 8;
                int4   da = *reinterpret_cast<const int4*>(dstp + e0);
                int4   db = *reinterpret_cast<const int4*>(dstp + e0 + 4);
                float4 wa = *reinterpret_cast<const float4*>(w + e0);
                float4 wb = *reinterpret_cast<const float4*>(w + e0 + 4);

                unsigned a0 = (unsigned)(da.x - lo), a1 = (unsigned)(da.y - lo),
                         a2 = (unsigned)(da.z - lo), a3 = (unsigned)(da.w - lo),
                         a4 = (unsigned)(db.x - lo), a5 = (unsigned)(db.y - lo),
                         a6 = (unsigned)(db.z - lo), a7 = (unsigned)(db.w - lo);
                // branchless LDS gather (clamped), predicated OR into packed words
                float v0 = bf16_to_f(xh[a0 < HALF_S ? a0 : 0u]);
                float v1 = bf16_to_f(xh[a1 < HALF_S ? a1 : 0u]);
                float v2 = bf16_to_f(xh[a2 < HALF_S ? a2 : 0u]);
                float v3 = bf16_to_f(xh[a3 < HALF_S ? a3 : 0u]);
                float v4 = bf16_to_f(xh[a4 < HALF_S ? a4 : 0u]);
                float v5 = bf16_to_f(xh[a5 < HALF_S ? a5 : 0u]);
                float v6 = bf16_to_f(xh[a6 < HALF_S ? a6 : 0u]);
                float v7 = bf16_to_f(xh[a7 < HALF_S ? a7 : 0u]);
                o[k].x |= (a0 < HALF_S ? bf16_rne(wa.x * v0)       : 0u)
                        | (a1 < HALF_S ? bf16_rne(wa.y * v1) << 16 : 0u);
                o[k].y |= (a2 < HALF_S ? bf16_rne(wa.z * v2)       : 0u)
                        | (a3 < HALF_S ? bf16_rne(wa.w * v3) << 16 : 0u);
                o[k].z |= (a4 < HALF_S ? bf16_rne(wb.x * v4)       : 0u)
                        | (a5 < HALF_S ? bf16_rne(wb.y * v5) << 16 : 0u);
                o[k].w |= (a6 < HALF_S ? bf16_rne(wb.z * v6)       : 0u)
                        | (a7 < HALF_S ? bf16_rne(wb.w * v7) << 16 : 0u);
            }
        }
    }

    #pragma unroll
    for (int k = 0; k < 4; ++k) {
        int idx = k * TTHREADS + tid;
        if (idx < GPB) {
            *reinterpret_cast<uint4*>(msg + base + idx * 8) = o[k];
        }
    }
}

// Phase 2: int32 fixed-point bins (R9-proven), 2 blocks/CU, XCD-sibling swizzle.
__global__ void __launch_bounds__(BLK) bin_kernel(
        const int* __restrict__ ei, const unsigned short* __restrict__ msg,
        int* __restrict__ partial) {
    __shared__ int bins[RANGE_S];   // 50 KB
    const int b    = blockIdx.x;    // 0..511
    const int xcd  = b & 7;
    const int slot = b >> 3;        // 0..63
    const int r    = slot & 7;      // range
    const int c    = (slot >> 3) * 8 + xcd;  // chunk 0..63 (siblings share XCD)

    for (int i = threadIdx.x; i < RANGE_S; i += BLK) bins[i] = 0;
    __syncthreads();

    const int chunk = N_EDGES / NB;   // 100000, % 8 == 0
    const int base  = c * chunk;
    const int end   = base + chunk;
    const int lo    = r * RANGE_S;

    for (int e = base + (int)threadIdx.x * 8; e < end; e += BLK * 8) {
        int4 sa = *reinterpret_cast<const int4*>(ei + e);
        int4 sb = *reinterpret_cast<const int4*>(ei + e + 4);
        uint4 mm = *reinterpret_cast<const uint4*>(msg + e);

        unsigned a[8] = {(unsigned)(sa.x-lo),(unsigned)(sa.y-lo),(unsigned)(sa.z-lo),(unsigned)(sa.w-lo),
                         (unsigned)(sb.x-lo),(unsigned)(sb.y-lo),(unsigned)(sb.z-lo),(unsigned)(sb.w-lo)};
        float f[8] = {
            __uint_as_float((mm.x & 0xFFFFu) << 16), __uint_as_float(mm.x & 0xFFFF0000u),
            __uint_as_float((mm.y & 0xFFFFu) << 16), __uint_as_float(mm.y & 0xFFFF0000u),
            __uint_as_float((mm.z & 0xFFFFu) << 16), __uint_as_float(mm.z & 0xFFFF0000u),
            __uint_as_float((mm.w & 0xFFFFu) << 16), __uint_as_float(mm.w & 0xFFFF0000u)
        };
        int mi[8];
        #pragma unroll
        for (int k = 0; k < 8; ++k) mi[k] = (int)__builtin_rintf(f[k] * FIX_SCALE);
        #pragma unroll
        for (int k = 0; k < 8; ++k) {
            if (a[k] < RANGE_S) atomicAdd(&bins[a[k]], mi[k]);   // integer LDS atomic
        }
    }
    __syncthreads();
    int* outp = partial + (size_t)(r * NB + c) * RANGE_S;
    for (int i = threadIdx.x; i < RANGE_S; i += BLK) outp[i] = bins[i];
}

// Reduce: exact integer sum of 64 chunk-partials, single float convert.
__global__ void reduce_range_kernel(const int* __restrict__ partial, float* __restrict__ out) {
    int i = blockIdx.x * blockDim.x + threadIdx.x;
    int n0 = i * 4;
    if (n0 >= N_NODES) return;
    int r = n0 / RANGE_S;
    int s = n0 - r * RANGE_S;          // RANGE_S % 4 == 0 -> no straddle
    const int* base = partial + (size_t)(r * NB) * RANGE_S + s;
    int4 acc = make_int4(0, 0, 0, 0);
    for (int j = 0; j < NB; ++j) {
        int4 v = *reinterpret_cast<const int4*>(base + (size_t)j * RANGE_S);
        acc.x += v.x; acc.y += v.y; acc.z += v.z; acc.w += v.w;
    }
    float4 o = make_float4((float)acc.x * FIX_INV, (float)acc.y * FIX_INV,
                           (float)acc.z * FIX_INV, (float)acc.w * FIX_INV);
    *reinterpret_cast<float4*>(out + n0) = o;
}

extern "C" void kernel_launch(void* const* d_in, const int* in_sizes, int n_in,
                              void* d_out, int out_size, void* d_ws, size_t ws_size,
                              hipStream_t stream) {
    const float* x   = (const float*)d_in[0];
    const int*   ei  = (const int*)d_in[1];
    const float* w   = (const float*)d_in[2];
    float*       out = (float*)d_out;

    const size_t msg_bytes     = (size_t)N_EDGES * 2;                 // 12.8 MB
    const size_t partial_bytes = (size_t)RANGES * NB * RANGE_S * 4;   // 25.6 MB

    if (ws_size >= msg_bytes + partial_bytes) {
        unsigned short* msg = (unsigned short*)d_ws;
        int* partial = (int*)((char*)d_ws + msg_bytes);
        transform_kernel<<<TBLOCKS, TTHREADS, 0, stream>>>(x, ei, w, msg);
        bin_kernel<<<RANGES * NB, BLK, 0, stream>>>(ei, msg, partial);
        reduce_range_kernel<<<(N_NODES / 4 + 255) / 256, 256, 0, stream>>>(partial, out);
    } else {
        zero_out_kernel<<<(N_NODES + 255) / 256, 256, 0, stream>>>(out, N_NODES);
        scatter_direct_kernel<<<(N_EDGES / 4 + 255) / 256, 256, 0, stream>>>(x, ei, w, out);
    }
}

// Round 12
// 48.072 us; speedup vs baseline: 1.3601x; 1.0020x over previous
//
#include <hip/hip_runtime.h>

#define N_NODES 100000
#define N_EDGES 6400000
#define RANGES 8
#define RANGE_S 12500   // nodes per range; RANGES * RANGE_S == N_NODES
#define NB 64           // chunks; chunk = 100000 edges
#define BLK 1024
#define FIX_SCALE 1048576.0f        // 2^20
#define FIX_INV   (1.0f / 1048576.0f)

// transform v4 geometry
#define TBLOCKS 256
#define TTHREADS 1024
#define EPB (N_EDGES / TBLOCKS)     // 25000 edges per block
#define GPB (EPB / 8)               // 3125 groups of 8
#define HALF_S 50000                // nodes per half (bf16 -> 100 KB LDS)
#define NP 2

// ============ fallback path A: direct device atomics ============
__global__ void zero_out_kernel(float* __restrict__ out, int n) {
    int i = blockIdx.x * blockDim.x + threadIdx.x;
    if (i < n) out[i] = 0.0f;
}

__global__ void __launch_bounds__(256) scatter_direct_kernel(
        const float* __restrict__ x, const int* __restrict__ ei,
        const float* __restrict__ w, float* __restrict__ out) {
    int t = blockIdx.x * blockDim.x + threadIdx.x;
    int e0 = t * 4;
    if (e0 >= N_EDGES) return;
    int4   s4 = *reinterpret_cast<const int4*>(ei + e0);
    int4   d4 = *reinterpret_cast<const int4*>(ei + N_EDGES + e0);
    float4 w4 = *reinterpret_cast<const float4*>(w + e0);
    atomicAdd(&out[s4.x], w4.x * x[d4.x]);
    atomicAdd(&out[s4.y], w4.y * x[d4.y]);
    atomicAdd(&out[s4.z], w4.z * x[d4.z]);
    atomicAdd(&out[s4.w], w4.w * x[d4.w]);
}

// ============ main path ============
__device__ __forceinline__ unsigned bf16_rne(float f) {
    unsigned b = __float_as_uint(f);
    b += 0x7FFFu + ((b >> 16) & 1u);
    return b >> 16;
}
__device__ __forceinline__ float bf16_to_f(unsigned short h) {
    return __uint_as_float(((unsigned)h) << 16);
}

// Phase 1 v4: LDS-staged gather with register edge-cache.
// Edges (dst,w) are loaded ONCE into registers (~80 VGPR) at entry;
// two bf16 x-half passes gather from LDS. Work-id swizzle aligns this
// block's msg writes with the XCD of the bin blocks that consume them.
__global__ void __launch_bounds__(TTHREADS, 4) transform_kernel(
        const float* __restrict__ x, const int* __restrict__ ei,
        const float* __restrict__ w, unsigned short* __restrict__ msg) {
    __shared__ unsigned short xh[HALF_S];   // 100 KB
    const int tid = threadIdx.x;
    // physical block B on XCD B%8; choose work b so that chunk c = b/4 has
    // (c % 8) == B % 8, matching bin_kernel's chunk->XCD mapping.
    const int B    = blockIdx.x;
    const int xcd  = B & 7;
    const int slot = B >> 3;                 // 0..31
    const int b    = (slot >> 2) * 32 + xcd * 4 + (slot & 3);
    const int base = b * EPB;
    const int* dstp = ei + N_EDGES;

    // ---- register edge-cache: 32 edges/thread, loaded once ----
    int4 da[4], db[4]; float4 wa[4], wb[4]; uint4 o[4];
    #pragma unroll
    for (int k = 0; k < 4; ++k) {
        const int idx = k * TTHREADS + tid;
        o[k] = make_uint4(0u, 0u, 0u, 0u);
        if (idx < GPB) {
            const int e0 = base + idx * 8;
            da[k] = *reinterpret_cast<const int4*>(dstp + e0);
            db[k] = *reinterpret_cast<const int4*>(dstp + e0 + 4);
            wa[k] = *reinterpret_cast<const float4*>(w + e0);
            wb[k] = *reinterpret_cast<const float4*>(w + e0 + 4);
        } else {
            da[k] = db[k] = make_int4(-1, -1, -1, -1);   // matches no half
            wa[k] = wb[k] = make_float4(0.f, 0.f, 0.f, 0.f);
        }
    }

    #pragma unroll
    for (int p = 0; p < NP; ++p) {
        if (p) __syncthreads();             // prior pass's LDS reads done
        // stage half p: 50000 floats -> bf16, coalesced
        const float4* xs = reinterpret_cast<const float4*>(x + p * HALF_S);
        for (int j = tid; j < HALF_S / 8; j += TTHREADS) {
            float4 f0 = xs[j * 2], f1 = xs[j * 2 + 1];
            uint4 pk;
            pk.x = bf16_rne(f0.x) | (bf16_rne(f0.y) << 16);
            pk.y = bf16_rne(f0.z) | (bf16_rne(f0.w) << 16);
            pk.z = bf16_rne(f1.x) | (bf16_rne(f1.y) << 16);
            pk.w = bf16_rne(f1.z) | (bf16_rne(f1.w) << 16);
            *reinterpret_cast<uint4*>(&xh[j * 8]) = pk;
        }
        __syncthreads();
        const int lo = p * HALF_S;

        #pragma unroll
        for (int k = 0; k < 4; ++k) {
            unsigned a0 = (unsigned)(da[k].x - lo), a1 = (unsigned)(da[k].y - lo),
                     a2 = (unsigned)(da[k].z - lo), a3 = (unsigned)(da[k].w - lo),
                     a4 = (unsigned)(db[k].x - lo), a5 = (unsigned)(db[k].y - lo),
                     a6 = (unsigned)(db[k].z - lo), a7 = (unsigned)(db[k].w - lo);
            float v0 = bf16_to_f(xh[a0 < HALF_S ? a0 : 0u]);
            float v1 = bf16_to_f(xh[a1 < HALF_S ? a1 : 0u]);
            float v2 = bf16_to_f(xh[a2 < HALF_S ? a2 : 0u]);
            float v3 = bf16_to_f(xh[a3 < HALF_S ? a3 : 0u]);
            float v4 = bf16_to_f(xh[a4 < HALF_S ? a4 : 0u]);
            float v5 = bf16_to_f(xh[a5 < HALF_S ? a5 : 0u]);
            float v6 = bf16_to_f(xh[a6 < HALF_S ? a6 : 0u]);
            float v7 = bf16_to_f(xh[a7 < HALF_S ? a7 : 0u]);
            o[k].x |= (a0 < HALF_S ? bf16_rne(wa[k].x * v0)       : 0u)
                    | (a1 < HALF_S ? bf16_rne(wa[k].y * v1) << 16 : 0u);
            o[k].y |= (a2 < HALF_S ? bf16_rne(wa[k].z * v2)       : 0u)
                    | (a3 < HALF_S ? bf16_rne(wa[k].w * v3) << 16 : 0u);
            o[k].z |= (a4 < HALF_S ? bf16_rne(wb[k].x * v4)       : 0u)
                    | (a5 < HALF_S ? bf16_rne(wb[k].y * v5) << 16 : 0u);
            o[k].w |= (a6 < HALF_S ? bf16_rne(wb[k].z * v6)       : 0u)
                    | (a7 < HALF_S ? bf16_rne(wb[k].w * v7) << 16 : 0u);
        }
    }

    #pragma unroll
    for (int k = 0; k < 4; ++k) {
        const int idx = k * TTHREADS + tid;
        if (idx < GPB) {
            *reinterpret_cast<uint4*>(msg + base + idx * 8) = o[k];
        }
    }
}

// Phase 2: int32 fixed-point bins, 2 blocks/CU, XCD-sibling swizzle. (R9-proven)
__global__ void __launch_bounds__(BLK) bin_kernel(
        const int* __restrict__ ei, const unsigned short* __restrict__ msg,
        int* __restrict__ partial) {
    __shared__ int bins[RANGE_S];   // 50 KB
    const int b    = blockIdx.x;    // 0..511
    const int xcd  = b & 7;
    const int slot = b >> 3;        // 0..63
    const int r    = slot & 7;      // range
    const int c    = (slot >> 3) * 8 + xcd;  // chunk 0..63 (siblings share XCD)

    for (int i = threadIdx.x; i < RANGE_S; i += BLK) bins[i] = 0;
    __syncthreads();

    const int chunk = N_EDGES / NB;   // 100000, % 8 == 0
    const int base  = c * chunk;
    const int end   = base + chunk;
    const int lo    = r * RANGE_S;

    for (int e = base + (int)threadIdx.x * 8; e < end; e += BLK * 8) {
        int4 sa = *reinterpret_cast<const int4*>(ei + e);
        int4 sb = *reinterpret_cast<const int4*>(ei + e + 4);
        uint4 mm = *reinterpret_cast<const uint4*>(msg + e);

        unsigned a[8] = {(unsigned)(sa.x-lo),(unsigned)(sa.y-lo),(unsigned)(sa.z-lo),(unsigned)(sa.w-lo),
                         (unsigned)(sb.x-lo),(unsigned)(sb.y-lo),(unsigned)(sb.z-lo),(unsigned)(sb.w-lo)};
        float f[8] = {
            __uint_as_float((mm.x & 0xFFFFu) << 16), __uint_as_float(mm.x & 0xFFFF0000u),
            __uint_as_float((mm.y & 0xFFFFu) << 16), __uint_as_float(mm.y & 0xFFFF0000u),
            __uint_as_float((mm.z & 0xFFFFu) << 16), __uint_as_float(mm.z & 0xFFFF0000u),
            __uint_as_float((mm.w & 0xFFFFu) << 16), __uint_as_float(mm.w & 0xFFFF0000u)
        };
        int mi[8];
        #pragma unroll
        for (int k = 0; k < 8; ++k) mi[k] = (int)__builtin_rintf(f[k] * FIX_SCALE);
        #pragma unroll
        for (int k = 0; k < 8; ++k) {
            if (a[k] < RANGE_S) atomicAdd(&bins[a[k]], mi[k]);   // integer LDS atomic
        }
    }
    __syncthreads();
    int* outp = partial + (size_t)(r * NB + c) * RANGE_S;
    for (int i = threadIdx.x; i < RANGE_S; i += BLK) outp[i] = bins[i];
}

// Reduce: exact integer sum of 64 chunk-partials, single float convert.
__global__ void reduce_range_kernel(const int* __restrict__ partial, float* __restrict__ out) {
    int i = blockIdx.x * blockDim.x + threadIdx.x;
    int n0 = i * 4;
    if (n0 >= N_NODES) return;
    int r = n0 / RANGE_S;
    int s = n0 - r * RANGE_S;          // RANGE_S % 4 == 0 -> no straddle
    const int* base = partial + (size_t)(r * NB) * RANGE_S + s;
    int4 acc = make_int4(0, 0, 0, 0);
    for (int j = 0; j < NB; ++j) {
        int4 v = *reinterpret_cast<const int4*>(base + (size_t)j * RANGE_S);
        acc.x += v.x; acc.y += v.y; acc.z += v.z; acc.w += v.w;
    }
    float4 o = make_float4((float)acc.x * FIX_INV, (float)acc.y * FIX_INV,
                           (float)acc.z * FIX_INV, (float)acc.w * FIX_INV);
    *reinterpret_cast<float4*>(out + n0) = o;
}

extern "C" void kernel_launch(void* const* d_in, const int* in_sizes, int n_in,
                              void* d_out, int out_size, void* d_ws, size_t ws_size,
                              hipStream_t stream) {
    const float* x   = (const float*)d_in[0];
    const int*   ei  = (const int*)d_in[1];
    const float* w   = (const float*)d_in[2];
    float*       out = (float*)d_out;

    const size_t msg_bytes     = (size_t)N_EDGES * 2;                 // 12.8 MB
    const size_t partial_bytes = (size_t)RANGES * NB * RANGE_S * 4;   // 25.6 MB

    if (ws_size >= msg_bytes + partial_bytes) {
        unsigned short* msg = (unsigned short*)d_ws;
        int* partial = (int*)((char*)d_ws + msg_bytes);
        transform_kernel<<<TBLOCKS, TTHREADS, 0, stream>>>(x, ei, w, msg);
        bin_kernel<<<RANGES * NB, BLK, 0, stream>>>(ei, msg, partial);
        reduce_range_kernel<<<(N_NODES / 4 + 255) / 256, 256, 0, stream>>>(partial, out);
    } else {
        zero_out_kernel<<<(N_NODES + 255) / 256, 256, 0, stream>>>(out, N_NODES);
        scatter_direct_kernel<<<(N_EDGES / 4 + 255) / 256, 256, 0, stream>>>(x, ei, w, out);
    }
}